// Round 4
// baseline (498.047 us; speedup 1.0000x reference)
//
#include <hip/hip_runtime.h>
#include <math.h>

#define NN 4096
#define NE 131072
#define DIM 256
#define NHEAD 8
#define HD 32

typedef __attribute__((ext_vector_type(8))) short short8v;
typedef __attribute__((ext_vector_type(4))) float f32x4;
#define MFMA16(a, b, c) __builtin_amdgcn_mfma_f32_16x16x32_bf16(a, b, c, 0, 0, 0)

__device__ __forceinline__ float elu_f(float v){ return v > 0.f ? v : expm1f(v); }
__device__ __forceinline__ float gelu_f(float v){
  const float c = 0.7978845608028654f;
  float t = tanhf(c * (v + 0.044715f * v * v * v));
  return 0.5f * v * (1.f + t);
}
__device__ __forceinline__ unsigned short f2bf(float f) {
  unsigned int u = __builtin_bit_cast(unsigned int, f);
  u += 0x7FFFu + ((u >> 16) & 1u);
  return (unsigned short)(u >> 16);
}

// ---------------- CSR build ----------------
__global__ void zero_counts(int* __restrict__ counts) {
  int i = blockIdx.x * 256 + threadIdx.x;
  if (i < NN) counts[i] = 0;
}

__global__ void count_edges(const int* __restrict__ ei, int* __restrict__ counts) {
  int e = blockIdx.x * 256 + threadIdx.x;
  if (e < NE) atomicAdd(&counts[ei[NE + e]], 1);
}

__global__ __launch_bounds__(1024) void scan_offsets(const int* __restrict__ counts,
                                                     int* __restrict__ offs,
                                                     int* __restrict__ cursor) {
  __shared__ int tmp[1024];
  int t = threadIdx.x;
  int base = t * 4;
  int c0 = counts[base], c1 = counts[base+1], c2 = counts[base+2], c3 = counts[base+3];
  int tsum = c0 + c1 + c2 + c3;
  tmp[t] = tsum;
  __syncthreads();
  for (int d = 1; d < 1024; d <<= 1) {
    int v = (t >= d) ? tmp[t - d] : 0;
    __syncthreads();
    tmp[t] += v;
    __syncthreads();
  }
  int excl = tmp[t] - tsum;
  offs[base]   = excl;           cursor[base]   = excl;
  offs[base+1] = excl + c0;      cursor[base+1] = excl + c0;
  offs[base+2] = excl + c0 + c1; cursor[base+2] = excl + c0 + c1;
  offs[base+3] = excl + c0 + c1 + c2; cursor[base+3] = excl + c0 + c1 + c2;
  if (t == 1023) offs[NN] = tmp[1023];
}

__global__ void scatter_edges(const int* __restrict__ ei, int* __restrict__ cursor,
                              int* __restrict__ esrc) {
  int e = blockIdx.x * 256 + threadIdx.x;
  if (e < NE) {
    int d = ei[NE + e];
    int pos = atomicAdd(&cursor[d], 1);
    esrc[pos] = ei[e];
  }
}

// block per node: aggb[n][c] = bf16( (1+eps)*x[n][c] + sum_{e} x[src_e][c] )
__global__ __launch_bounds__(256) void gin_agg(const int* __restrict__ offs,
                                               const int* __restrict__ esrc,
                                               const float* __restrict__ x,
                                               const float* __restrict__ eps_p, int l,
                                               unsigned short* __restrict__ aggb) {
  int n = blockIdx.x, c = threadIdx.x;
  int e0 = offs[n], e1 = offs[n + 1];
  float acc = 0.f;
  for (int e = e0; e < e1; e++) acc += x[(size_t)esrc[e] * DIM + c];
  float eps = eps_p[l];
  aggb[(size_t)n * DIM + c] = f2bf((1.f + eps) * x[(size_t)n * DIM + c] + acc);
}

// ---------------- bf16 MFMA GEMM: C = act(A @ W^T + bias) ----------------
template<int ACT, int WF32, int WBF16, int QSCALE>
__global__ __launch_bounds__(256) void gemm_mfma(
    const unsigned short* __restrict__ A, const unsigned short* __restrict__ W,
    const float* __restrict__ bias, float* __restrict__ Cf,
    unsigned short* __restrict__ Cb, int M, int N, int K)
{
  __shared__ __align__(16) unsigned short As[64][40];
  __shared__ __align__(16) unsigned short Ws[64][40];
  int t = threadIdx.x;
  int w = t >> 6, lane = t & 63, lo = lane & 15, g = lane >> 4;
  int wr = w >> 1, wc = w & 1;
  int bn = blockIdx.x * 64, bm = blockIdx.y * 64;
  int srow = t >> 2, skk = (t & 3) << 3;
  const unsigned short* ap = A + (size_t)(bm + srow) * K + skk;
  const unsigned short* wp = W + (size_t)(bn + srow) * K + skk;

  f32x4 acc[2][2] = {{{0.f,0.f,0.f,0.f},{0.f,0.f,0.f,0.f}},
                     {{0.f,0.f,0.f,0.f},{0.f,0.f,0.f,0.f}}};

  for (int k0 = 0; k0 < K; k0 += 32) {
    *(short8v*)&As[srow][skk] = *(const short8v*)(ap + k0);
    *(short8v*)&Ws[srow][skk] = *(const short8v*)(wp + k0);
    __syncthreads();
    short8v a0 = *(const short8v*)&As[wr * 32 + lo][8 * g];
    short8v a1 = *(const short8v*)&As[wr * 32 + 16 + lo][8 * g];
    short8v b0 = *(const short8v*)&Ws[wc * 32 + lo][8 * g];
    short8v b1 = *(const short8v*)&Ws[wc * 32 + 16 + lo][8 * g];
    acc[0][0] = MFMA16(a0, b0, acc[0][0]);
    acc[0][1] = MFMA16(a0, b1, acc[0][1]);
    acc[1][0] = MFMA16(a1, b0, acc[1][0]);
    acc[1][1] = MFMA16(a1, b1, acc[1][1]);
    __syncthreads();
  }

  #pragma unroll
  for (int mi = 0; mi < 2; mi++) {
    #pragma unroll
    for (int ni = 0; ni < 2; ni++) {
      #pragma unroll
      for (int r = 0; r < 4; r++) {
        int row = bm + wr * 32 + mi * 16 + 4 * g + r;
        int col = bn + wc * 32 + ni * 16 + lo;
        float v = acc[mi][ni][r] + bias[col];
        if (ACT == 1) v = elu_f(v);
        if (ACT == 2) v = gelu_f(v);
        if (QSCALE) { if (col < 256) v *= 0.17677669529663687f; }
        if (WF32) Cf[(size_t)row * N + col] = v;
        if (WBF16) Cb[(size_t)row * N + col] = f2bf(v);
      }
    }
  }
}

// ---------------- LayerNorm(+act) + residual add; also emits bf16 copy ----------------
template<int ACT>
__global__ __launch_bounds__(256) void ln_act_add(const float* __restrict__ in,
                                                  const float* __restrict__ g,
                                                  const float* __restrict__ b,
                                                  float* __restrict__ x,
                                                  unsigned short* __restrict__ xb) {
  int rowb = blockIdx.x;
  int c = threadIdx.x;
  float v = in[(size_t)rowb * DIM + c];
  float s = v, s2 = v * v;
  #pragma unroll
  for (int off = 32; off >= 1; off >>= 1) {
    s  += __shfl_xor(s,  off, 64);
    s2 += __shfl_xor(s2, off, 64);
  }
  __shared__ float ws1[4], ws2[4];
  int w = threadIdx.x >> 6, lane = threadIdx.x & 63;
  if (lane == 0) { ws1[w] = s; ws2[w] = s2; }
  __syncthreads();
  s  = ws1[0] + ws1[1] + ws1[2] + ws1[3];
  s2 = ws2[0] + ws2[1] + ws2[2] + ws2[3];
  float mean = s * (1.f / DIM);
  float var = s2 * (1.f / DIM) - mean * mean;
  float r = rsqrtf(var + 1e-5f);
  float o = (v - mean) * r * g[c] + b[c];
  if (ACT == 1) o = elu_f(o);
  float nx = x[(size_t)rowb * DIM + c] + o;
  x[(size_t)rowb * DIM + c] = nx;
  xb[(size_t)rowb * DIM + c] = f2bf(nx);
}

// ---------------- V transpose ----------------
__global__ __launch_bounds__(256) void vt_transpose(const unsigned short* __restrict__ tbb,
                                                    unsigned short* __restrict__ VT) {
  __shared__ unsigned short lds[128][33];
  int h = blockIdx.y;
  int nb = blockIdx.x * 128;
  int tid = threadIdx.x;
  int r8 = tid >> 5, d = tid & 31;
  #pragma unroll
  for (int i = 0; i < 16; i++) {
    int n = i * 8 + r8;
    lds[n][d] = tbb[(size_t)(nb + n) * 768 + 512 + h * 32 + d];
  }
  __syncthreads();
  int dd = tid >> 7, j = tid & 127;
  #pragma unroll
  for (int i = 0; i < 16; i++) {
    int d2 = i * 2 + dd;
    VT[((size_t)h * 32 + d2) * 4096 + nb + j] = lds[j][d2];
  }
}

__device__ __forceinline__ int pswz(int q, int col) {
  return (col & 7) | ((((col >> 3) ^ q) & 7) << 3);
}

// ---------------- MFMA flash attention, k-split ----------------
// each block: 4 waves x 16 q-rows, head = blockIdx.y, k-span = blockIdx.z
// writes unnormalized partial O (f32) + (m, l) per (split, q, head)
__global__ __launch_bounds__(256) void attn_mfma_split(
    const unsigned short* __restrict__ qkvb, const unsigned short* __restrict__ VT,
    float* __restrict__ po, float* __restrict__ ml, int kspan) {
  __shared__ __align__(16) unsigned short plds[4][16][64];
  int tid = threadIdx.x;
  int w = tid >> 6, lane = tid & 63;
  int lo = lane & 15, g = lane >> 4;
  int h = blockIdx.y;
  int s = blockIdx.z;
  int qb = blockIdx.x * 64 + w * 16;
  int k_lo = s * kspan, k_hi = k_lo + kspan;

  short8v qf = *(const short8v*)(qkvb + (size_t)(qb + lo) * 768 + h * 32 + 8 * g);

  f32x4 acc0 = {0.f, 0.f, 0.f, 0.f};
  f32x4 acc1 = {0.f, 0.f, 0.f, 0.f};
  float mr[4] = {-1e30f, -1e30f, -1e30f, -1e30f};
  float lr[4] = {0.f, 0.f, 0.f, 0.f};

  const unsigned short* Kb = qkvb + 256 + h * 32 + 8 * g;
  const unsigned short* Vb = VT + (size_t)h * 32 * 4096 + 8 * g;
  const f32x4 zf = {0.f, 0.f, 0.f, 0.f};

  for (int kb = k_lo; kb < k_hi; kb += 64) {
    short8v kf0 = *(const short8v*)(Kb + (size_t)(kb +  0 + lo) * 768);
    short8v kf1 = *(const short8v*)(Kb + (size_t)(kb + 16 + lo) * 768);
    short8v kf2 = *(const short8v*)(Kb + (size_t)(kb + 32 + lo) * 768);
    short8v kf3 = *(const short8v*)(Kb + (size_t)(kb + 48 + lo) * 768);
    f32x4 s0 = MFMA16(qf, kf0, zf);
    f32x4 s1 = MFMA16(qf, kf1, zf);
    f32x4 s2 = MFMA16(qf, kf2, zf);
    f32x4 s3 = MFMA16(qf, kf3, zf);

    #pragma unroll
    for (int r = 0; r < 4; r++) {
      float t = fmaxf(fmaxf(s0[r], s1[r]), fmaxf(s2[r], s3[r]));
      t = fmaxf(t, __shfl_xor(t, 1, 64));
      t = fmaxf(t, __shfl_xor(t, 2, 64));
      t = fmaxf(t, __shfl_xor(t, 4, 64));
      t = fmaxf(t, __shfl_xor(t, 8, 64));
      float nm = fmaxf(mr[r], t);
      float f = __expf(mr[r] - nm);
      mr[r] = nm;
      float p0 = __expf(s0[r] - nm), p1 = __expf(s1[r] - nm);
      float p2 = __expf(s2[r] - nm), p3 = __expf(s3[r] - nm);
      lr[r] = lr[r] * f + (p0 + p1 + p2 + p3);
      acc0[r] *= f; acc1[r] *= f;
      int q = 4 * g + r;
      plds[w][q][pswz(q, lo)]      = f2bf(p0);
      plds[w][q][pswz(q, lo + 16)] = f2bf(p1);
      plds[w][q][pswz(q, lo + 32)] = f2bf(p2);
      plds[w][q][pswz(q, lo + 48)] = f2bf(p3);
    }

    short8v pa0 = *(const short8v*)&plds[w][lo][pswz(lo, 8 * g)];
    short8v pa1 = *(const short8v*)&plds[w][lo][pswz(lo, 32 + 8 * g)];
    short8v vf00 = *(const short8v*)(Vb + (size_t)(lo)      * 4096 + kb);
    short8v vf01 = *(const short8v*)(Vb + (size_t)(lo)      * 4096 + kb + 32);
    short8v vf10 = *(const short8v*)(Vb + (size_t)(lo + 16) * 4096 + kb);
    short8v vf11 = *(const short8v*)(Vb + (size_t)(lo + 16) * 4096 + kb + 32);
    acc0 = MFMA16(pa0, vf00, acc0);
    acc0 = MFMA16(pa1, vf01, acc0);
    acc1 = MFMA16(pa0, vf10, acc1);
    acc1 = MFMA16(pa1, vf11, acc1);
  }

  #pragma unroll
  for (int r = 0; r < 4; r++) {
    float t = lr[r];
    t += __shfl_xor(t, 1, 64);
    t += __shfl_xor(t, 2, 64);
    t += __shfl_xor(t, 4, 64);
    t += __shfl_xor(t, 8, 64);
    int q = qb + 4 * g + r;
    float* pr = po + ((size_t)s * NN + q) * DIM + h * 32;
    pr[lo]      = acc0[r];
    pr[16 + lo] = acc1[r];
    if (lo == 0) {
      float* mlp = ml + (((size_t)s * NN + q) * NHEAD + h) * 2;
      mlp[0] = mr[r];
      mlp[1] = t;
    }
  }
}

// combine k-splits: attb[q][c] = sum_s e^{m_s-M} po_s / sum_s e^{m_s-M} l_s
__global__ __launch_bounds__(256) void attn_merge(const float* __restrict__ po,
                                                  const float* __restrict__ ml,
                                                  unsigned short* __restrict__ attb, int S) {
  int q = blockIdx.x;
  int c = threadIdx.x;
  int h = c >> 5;
  float M = -1e30f;
  for (int s = 0; s < S; s++)
    M = fmaxf(M, ml[(((size_t)s * NN + q) * NHEAD + h) * 2]);
  float L = 0.f, O = 0.f;
  for (int s = 0; s < S; s++) {
    const float* mlp = ml + (((size_t)s * NN + q) * NHEAD + h) * 2;
    float e = __expf(mlp[0] - M);
    L += e * mlp[1];
    O += e * po[((size_t)s * NN + q) * DIM + c];
  }
  attb[(size_t)q * DIM + c] = f2bf(O / L);
}

// ---------------- weight conversion ----------------
#define WO0 0
#define WO1 131072
#define WO2 262144
#define WO3 655360
#define WO4 786432
#define WO5 1048576
#define WO6 1310720
#define WTOT 1343488
__global__ __launch_bounds__(256) void wconv(const float* __restrict__ s0, const float* __restrict__ s1,
                                             const float* __restrict__ s2, const float* __restrict__ s3,
                                             const float* __restrict__ s4, const float* __restrict__ s5,
                                             const float* __restrict__ s6, unsigned short* __restrict__ dst) {
  int i4 = (blockIdx.x * 256 + threadIdx.x) * 4;
  if (i4 >= WTOT) return;
  const float* src; int loc;
  if      (i4 < WO1) { src = s0; loc = i4 - WO0; }
  else if (i4 < WO2) { src = s1; loc = i4 - WO1; }
  else if (i4 < WO3) { src = s2; loc = i4 - WO2; }
  else if (i4 < WO4) { src = s3; loc = i4 - WO3; }
  else if (i4 < WO5) { src = s4; loc = i4 - WO4; }
  else if (i4 < WO6) { src = s5; loc = i4 - WO5; }
  else               { src = s6; loc = i4 - WO6; }
  float4 v = *(const float4*)(src + loc);
  ushort4 o;
  o.x = f2bf(v.x); o.y = f2bf(v.y); o.z = f2bf(v.z); o.w = f2bf(v.w);
  *(ushort4*)(dst + i4) = o;
}

__global__ __launch_bounds__(256) void pad72_96(const float* __restrict__ src,
                                                unsigned short* __restrict__ dst, int total) {
  int idx = blockIdx.x * 256 + threadIdx.x;
  if (idx >= total) return;
  int row = idx / 96, col = idx - row * 96;
  dst[idx] = (col < 72) ? f2bf(src[row * 72 + col]) : (unsigned short)0;
}

// ---------------- tiny head ----------------
__global__ void head2_kernel(const float* __restrict__ e, const float* __restrict__ w,
                             const float* __restrict__ b, float* __restrict__ out) {
  int idx = blockIdx.x * 256 + threadIdx.x;
  if (idx >= NN * 5) return;
  int rowi = idx / 5, col = idx % 5;
  float s = b[col];
  const float* ep = e + (size_t)rowi * 128;
  const float* wp = w + (size_t)col * 128;
  #pragma unroll 16
  for (int k = 0; k < 128; k++) s += ep[k] * wp[k];
  out[idx] = s;
}

extern "C" void kernel_launch(void* const* d_in, const int* in_sizes, int n_in,
                              void* d_out, int out_size, void* d_ws, size_t ws_size,
                              hipStream_t stream) {
  const float* x_in   = (const float*)d_in[0];
  const int*   ei     = (const int*)  d_in[1];
  const float* in_w   = (const float*)d_in[2];
  const float* in_b   = (const float*)d_in[3];
  const float* head_w1= (const float*)d_in[4];
  const float* head_b1= (const float*)d_in[5];
  const float* head_w2= (const float*)d_in[6];
  const float* head_b2= (const float*)d_in[7];
  const float* mlp_w1 = (const float*)d_in[8];
  const float* mlp_b1 = (const float*)d_in[9];
  const float* mlp_w2 = (const float*)d_in[10];
  const float* mlp_b2 = (const float*)d_in[11];
  const float* gin_eps= (const float*)d_in[12];
  const float* ln1_g  = (const float*)d_in[13];
  const float* ln1_b  = (const float*)d_in[14];
  const float* attn_in_w = (const float*)d_in[15];
  const float* attn_in_b = (const float*)d_in[16];
  const float* attn_out_w= (const float*)d_in[17];
  const float* attn_out_b= (const float*)d_in[18];
  const float* ln2_g  = (const float*)d_in[19];
  const float* ln2_b  = (const float*)d_in[20];
  const float* ffn_w1 = (const float*)d_in[21];
  const float* ffn_b1 = (const float*)d_in[22];
  const float* ffn_w2 = (const float*)d_in[23];
  const float* ffn_b2 = (const float*)d_in[24];
  const float* ln3_g  = (const float*)d_in[25];
  const float* ln3_b  = (const float*)d_in[26];

  float* ws = (float*)d_ws;
  float* x    = ws;                              // [NN,256] f32
  float* t2   = x  + (size_t)NN * DIM;           // [NN,256] f32
  float* he   = t2 + (size_t)NN * DIM;           // [NN,128] f32
  unsigned short* xb   = (unsigned short*)(he + (size_t)NN * 128);
  unsigned short* tbb  = xb   + (size_t)NN * DIM;       // [NN,768] bf16
  unsigned short* aggb = tbb  + (size_t)NN * 768;       // [NN,256] bf16
  unsigned short* attb = aggb + (size_t)NN * DIM;       // [NN,256] bf16
  unsigned short* VT   = attb + (size_t)NN * DIM;       // [256][NN] bf16
  unsigned short* xinb = VT   + (size_t)NN * DIM;       // [NN][96] bf16
  unsigned short* inwb = xinb + (size_t)NN * 96;        // [256][96] bf16
  unsigned short* warena = inwb + 256 * 96;             // WTOT bf16
  int* counts = (int*)(warena + WTOT);
  int* offs   = counts + NN;       // NN+1
  int* cursor = offs + NN + 1;
  int* esrc   = cursor + NN;       // NE
  float* po   = (float*)(esrc + NE);   // [S][NN][DIM] f32
  // pick split factor by available scratch
  size_t used_f = (size_t)(po - ws);
  int S = 1;
  for (int cand = 4; cand >= 2; cand >>= 1) {
    size_t need = (used_f + (size_t)cand * NN * DIM + (size_t)cand * NN * NHEAD * 2) * 4;
    if (ws_size >= need) { S = cand; break; }
  }
  float* ml = po + (size_t)S * NN * DIM;
  int kspan = NN / S;

  const unsigned short* w_mlp1 = warena + WO0;
  const unsigned short* w_mlp2 = warena + WO1;
  const unsigned short* w_qkv  = warena + WO2;
  const unsigned short* w_aout = warena + WO3;
  const unsigned short* w_ffn1 = warena + WO4;
  const unsigned short* w_ffn2 = warena + WO5;
  const unsigned short* w_h1   = warena + WO6;

  // CSR build
  zero_counts<<<16, 256, 0, stream>>>(counts);
  count_edges<<<NE / 256, 256, 0, stream>>>(ei, counts);
  scan_offsets<<<1, 1024, 0, stream>>>(counts, offs, cursor);
  scatter_edges<<<NE / 256, 256, 0, stream>>>(ei, cursor, esrc);

  // weight + input conversions
  wconv<<<1312, 256, 0, stream>>>(mlp_w1, mlp_w2, attn_in_w, attn_out_w, ffn_w1, ffn_w2,
                                  head_w1, warena);
  pad72_96<<<(NN * 96 + 255) / 256, 256, 0, stream>>>(x_in, xinb, NN * 96);
  pad72_96<<<(256 * 96 + 255) / 256, 256, 0, stream>>>(in_w, inwb, 256 * 96);

  // input projection
  gemm_mfma<1,1,1,0><<<dim3(DIM/64, NN/64), 256, 0, stream>>>(xinb, inwb, in_b, x, xb,
                                                              NN, DIM, 96);

  for (int l = 0; l < 2; l++) {
    // GIN
    gin_agg<<<NN, 256, 0, stream>>>(offs, esrc, x, gin_eps, l, aggb);
    gemm_mfma<1,0,1,0><<<dim3(4, 64), 256, 0, stream>>>(aggb, w_mlp1 + (size_t)l*65536,
                                                        mlp_b1 + l*DIM, nullptr, tbb,
                                                        NN, DIM, DIM);
    gemm_mfma<0,1,0,0><<<dim3(4, 64), 256, 0, stream>>>(tbb, w_mlp2 + (size_t)l*65536,
                                                        mlp_b2 + l*DIM, t2, nullptr,
                                                        NN, DIM, DIM);
    ln_act_add<1><<<NN, 256, 0, stream>>>(t2, ln1_g + l*DIM, ln1_b + l*DIM, x, xb);

    // attention
    gemm_mfma<0,0,1,1><<<dim3(12, 64), 256, 0, stream>>>(xb, w_qkv + (size_t)l*196608,
                                                         attn_in_b + l*768, nullptr, tbb,
                                                         NN, 768, DIM);
    vt_transpose<<<dim3(32, 8), 256, 0, stream>>>(tbb, VT);
    attn_mfma_split<<<dim3(64, NHEAD, S), 256, 0, stream>>>(tbb, VT, po, ml, kspan);
    attn_merge<<<NN, 256, 0, stream>>>(po, ml, attb, S);
    gemm_mfma<0,1,0,0><<<dim3(4, 64), 256, 0, stream>>>(attb, w_aout + (size_t)l*65536,
                                                        attn_out_b + l*DIM, t2, nullptr,
                                                        NN, DIM, DIM);
    ln_act_add<0><<<NN, 256, 0, stream>>>(t2, ln2_g + l*DIM, ln2_b + l*DIM, x, xb);

    // FFN
    gemm_mfma<2,0,1,0><<<dim3(8, 64), 256, 0, stream>>>(xb, w_ffn1 + (size_t)l*131072,
                                                        ffn_b1 + l*512, nullptr, tbb,
                                                        NN, 512, DIM);
    gemm_mfma<0,1,0,0><<<dim3(4, 64), 256, 0, stream>>>(tbb, w_ffn2 + (size_t)l*131072,
                                                        ffn_b2 + l*DIM, t2, nullptr,
                                                        NN, DIM, 512);
    ln_act_add<0><<<NN, 256, 0, stream>>>(t2, ln3_g + l*DIM, ln3_b + l*DIM, x, xb);
  }

  // head
  gemm_mfma<1,1,0,0><<<dim3(2, 64), 256, 0, stream>>>(xb, w_h1, head_b1, he, nullptr,
                                                      NN, 128, DIM);
  head2_kernel<<<(NN * 5 + 255) / 256, 256, 0, stream>>>(he, head_w2, head_b2, (float*)d_out);
}